// Round 1
// baseline (352.326 us; speedup 1.0000x reference)
//
#include <hip/hip_runtime.h>

#define NS 4096
#define NC 32
#define NA 500
#define NV 125   // NA/4 float4 columns per row
#define MIN_VALUE 0.01f

__global__ __launch_bounds__(128) void gamma_obo_kernel(
    const float* __restrict__ x,   // (NS, NC, NA)
    const float* __restrict__ W,   // (1, NC)
    const float* __restrict__ b,   // (1,)
    float* __restrict__ out)       // (NS,)
{
    const int s = blockIdx.x;
    const int t = threadIdx.x;     // 0..127

    // Broadcast weights into registers (uniform across block, L1-cached).
    float w[NC];
#pragma unroll
    for (int c = 0; c < NC; ++c) w[c] = W[c];
    const float bias = b[0];

    float partial = 0.0f;
    if (t < NV) {
        const float4* __restrict__ xrow =
            (const float4*)(x + (size_t)s * (NC * NA));
        float4 acc = make_float4(bias, bias, bias, bias);
#pragma unroll
        for (int c = 0; c < NC; ++c) {
            float4 v = xrow[c * NV + t];
            acc.x = fmaf(w[c], v.x, acc.x);
            acc.y = fmaf(w[c], v.y, acc.y);
            acc.z = fmaf(w[c], v.z, acc.z);
            acc.w = fmaf(w[c], v.w, acc.w);
        }
        partial = fabsf(acc.x) + fabsf(acc.y) + fabsf(acc.z) + fabsf(acc.w);
    }

    // Wave-level butterfly reduce (wave = 64 lanes on gfx950).
#pragma unroll
    for (int off = 32; off > 0; off >>= 1)
        partial += __shfl_down(partial, off, 64);

    __shared__ float smem[2];
    if ((t & 63) == 0) smem[t >> 6] = partial;
    __syncthreads();

    if (t == 0) {
        float total = smem[0] + smem[1];
        out[s] = total / (float)NA + MIN_VALUE;
    }
}

extern "C" void kernel_launch(void* const* d_in, const int* in_sizes, int n_in,
                              void* d_out, int out_size, void* d_ws, size_t ws_size,
                              hipStream_t stream) {
    const float* x = (const float*)d_in[0];
    const float* W = (const float*)d_in[1];
    const float* b = (const float*)d_in[2];
    float* out = (float*)d_out;
    gamma_obo_kernel<<<NS, 128, 0, stream>>>(x, W, b, out);
}